// Round 5
// baseline (623.289 us; speedup 1.0000x reference)
//
#include <hip/hip_runtime.h>
#include <math.h>

#define N_NODES 100000
#define N_EDGES 1600000
#define IN_F    128
#define NH1     8
#define HID     8
#define C1      64   // NH1*HID
#define C2      40   // N_CLASSES
#define SCAN_B  256
#define N_SBLK  ((N_NODES + SCAN_B - 1) / SCAN_B)   // 391

typedef unsigned short ushort_t;
typedef unsigned int uint_t;

__device__ __forceinline__ float lrelu(float x) { return x > 0.f ? x : 0.2f * x; }
__device__ __forceinline__ ushort_t f2bf(float f) {
    uint_t u = __float_as_uint(f);
    u = (u + 0x7FFFu + ((u >> 16) & 1u)) >> 16;   // round-to-nearest-even
    return (ushort_t)u;
}
__device__ __forceinline__ float bf2f(ushort_t s) {
    return __uint_as_float(((uint_t)s) << 16);
}

// ---- K1: H1(bf16) = x@W1 ; s1[n,h], d1[n,h] attention dots. 4 nodes/block ----
__global__ __launch_bounds__(256) void k_gemm1(
    const float* __restrict__ x, const float* __restrict__ W1,
    const float* __restrict__ as1, const float* __restrict__ ad1,
    ushort_t* __restrict__ H1, float* __restrict__ s1, float* __restrict__ d1)
{
    __shared__ float xs[4][IN_F];
    int wv = threadIdx.x >> 6, lane = threadIdx.x & 63;
    int n = blockIdx.x * 4 + wv;
    ((float2*)xs[wv])[lane] = ((const float2*)(x + (size_t)n * IN_F))[lane];
    __syncthreads();
    float acc = 0.f;
    #pragma unroll
    for (int k = 0; k < IN_F; k += 4) {
        float4 xk = *(const float4*)&xs[wv][k];
        acc = fmaf(xk.x, W1[(k + 0) * C1 + lane], acc);
        acc = fmaf(xk.y, W1[(k + 1) * C1 + lane], acc);
        acc = fmaf(xk.z, W1[(k + 2) * C1 + lane], acc);
        acc = fmaf(xk.w, W1[(k + 3) * C1 + lane], acc);
    }
    H1[(size_t)n * C1 + lane] = f2bf(acc);
    float ps = acc * as1[lane], pd = acc * ad1[lane];  // lane == h*8+f
    #pragma unroll
    for (int off = 4; off; off >>= 1) {
        ps += __shfl_xor(ps, off);
        pd += __shfl_xor(pd, off);
    }
    if ((lane & 7) == 0) {
        s1[n * NH1 + (lane >> 3)] = ps;
        d1[n * NH1 + (lane >> 3)] = pd;
    }
}

// ---- CSR build: degree count ----
__global__ __launch_bounds__(256) void k_count(
    const int* __restrict__ ei, int* __restrict__ deg)
{
    int e = blockIdx.x * blockDim.x + threadIdx.x;
    if (e >= N_EDGES) return;
    atomicAdd(&deg[ei[N_EDGES + e]], 1);
}

// ---- scan phase 1: per-block (256-wide) reduction of deg -> bsum ----
__global__ __launch_bounds__(SCAN_B) void k_red(
    const int* __restrict__ deg, int* __restrict__ bsum)
{
    int t = threadIdx.x, lane = t & 63, wv = t >> 6;
    int i = blockIdx.x * SCAN_B + t;
    int v = (i < N_NODES) ? deg[i] : 0;
    #pragma unroll
    for (int off = 32; off; off >>= 1) v += __shfl_xor(v, off);
    __shared__ int s[4];
    if (lane == 0) s[wv] = v;
    __syncthreads();
    if (t == 0) bsum[blockIdx.x] = s[0] + s[1] + s[2] + s[3];
}

// ---- scan phase 2: single small block scans the 391 block sums ----
__global__ __launch_bounds__(512) void k_scan_small(
    const int* __restrict__ bsum, int* __restrict__ boff,
    int* __restrict__ rowptr)
{
    __shared__ int s[512];
    int t = threadIdx.x;
    int v = (t < N_SBLK) ? bsum[t] : 0;
    s[t] = v;
    __syncthreads();
    for (int off = 1; off < 512; off <<= 1) {
        int u = (t >= off) ? s[t - off] : 0;
        __syncthreads();
        s[t] += u;
        __syncthreads();
    }
    if (t < N_SBLK) boff[t] = s[t] - v;          // exclusive
    if (t == 511) rowptr[N_NODES] = s[511];      // total == N_EDGES
}

// ---- scan phase 3: in-block exclusive scan + block offset -> rowptr ----
__global__ __launch_bounds__(SCAN_B) void k_apply(
    const int* __restrict__ deg, const int* __restrict__ boff,
    int* __restrict__ rowptr)
{
    int t = threadIdx.x, lane = t & 63, wv = t >> 6;
    int i = blockIdx.x * SCAN_B + t;
    int v = (i < N_NODES) ? deg[i] : 0;
    int inc = v;
    #pragma unroll
    for (int off = 1; off < 64; off <<= 1) {
        int u = __shfl_up(inc, off);
        if (lane >= off) inc += u;
    }
    __shared__ int ws_[4];
    if (lane == 63) ws_[wv] = inc;
    __syncthreads();
    int add = 0;
    for (int k = 0; k < wv; k++) add += ws_[k];
    if (i < N_NODES) rowptr[i] = inc - v + add + boff[blockIdx.x];
}

// ---- CSR build: fill packed (src, edge_w) pairs ----
__global__ __launch_bounds__(256) void k_fill(
    const int* __restrict__ ei, const float* __restrict__ ea,
    const int* __restrict__ rowptr, int* __restrict__ cur,
    int2* __restrict__ edges)
{
    int e = blockIdx.x * blockDim.x + threadIdx.x;
    if (e >= N_EDGES) return;
    int s = ei[e], d = ei[N_EDGES + e];
    int pos = rowptr[d] + atomicAdd(&cur[d], 1);
    edges[pos] = make_int2(s, __float_as_int(ea[e]));
}

// ---- K_node1: wave per dst node, 8-edge batched logits.
//      Logit phase: lane = e*8 + h (8 edges x 8 heads, one expf for all).
//      Aggregation: lane = h*8 + f; p/src broadcast via shfl; 8 independent
//      H1-row gathers in flight. Then fused elu + GEMM2 + s2/d2 dots. ----
__global__ __launch_bounds__(256) void k_node1(
    const int* __restrict__ rowptr, const int2* __restrict__ edges,
    const float* __restrict__ s1, const float* __restrict__ d1,
    const float* __restrict__ ae1, const ushort_t* __restrict__ H1,
    const float* __restrict__ W2, const float* __restrict__ as2,
    const float* __restrict__ ad2,
    ushort_t* __restrict__ H2, float* __restrict__ s2, float* __restrict__ d2)
{
    int w = (blockIdx.x * blockDim.x + threadIdx.x) >> 6;
    int lane = threadIdx.x & 63;
    if (w >= N_NODES) return;
    int hA = lane >> 3;          // aggregation head (lane = hA*8 + f)
    int hL = lane & 7;           // logit-phase head  (lane = eL*8 + hL)
    int eL = lane >> 3;          // logit-phase edge slot
    float d1L = d1[w * NH1 + hL];
    float aeL = ae1[hL];
    int jb = rowptr[w], je = rowptr[w + 1];
    float den = 0.f, acc = 0.f;
    for (int base = jb; base < je; base += 8) {
        int idx = base + eL;
        bool valid = idx < je;
        int2 ed = edges[valid ? idx : jb];
        float l = lrelu(s1[ed.x * NH1 + hL] + d1L + __int_as_float(ed.y) * aeL);
        float p = valid ? __expf(l) : 0.f;
        int cnt = min(8, je - base);
        #pragma unroll 4
        for (int e = 0; e < cnt; ++e) {
            float pe = __shfl(p, e * 8 + hA);
            int   se = __shfl(ed.x, e * 8);
            den += pe;
            acc = fmaf(pe, bf2f(H1[(size_t)se * C1 + lane]), acc);
        }
    }
    float o = acc / (den + 1e-16f);
    float r = o > 0.f ? o : __expf(o) - 1.f;   // elu
    int c = lane < C2 ? lane : 0;
    float h2 = 0.f;
    #pragma unroll 8
    for (int k = 0; k < C1; ++k) {
        float rk = __shfl(r, k);
        h2 = fmaf(rk, W2[k * C2 + c], h2);
    }
    float ps = lane < C2 ? h2 * as2[c] : 0.f;
    float pd = lane < C2 ? h2 * ad2[c] : 0.f;
    #pragma unroll
    for (int off = 32; off; off >>= 1) {
        ps += __shfl_xor(ps, off);
        pd += __shfl_xor(pd, off);
    }
    if (lane < C2) H2[(size_t)w * C1 + lane] = f2bf(h2);  // stride 64 (padded)
    if (lane == 0) { s2[w] = ps; d2[w] = pd; }
}

// ---- K_node2: wave per dst node, 64-edge batched logits (1 head).
//      Aggregation inner loop over valid count: 2 shfl + 1 independent
//      H2 gather per edge. Fused log_softmax. ----
__global__ __launch_bounds__(256) void k_node2(
    const int* __restrict__ rowptr, const int2* __restrict__ edges,
    const float* __restrict__ s2, const float* __restrict__ d2,
    const float* __restrict__ ae2, const ushort_t* __restrict__ H2,
    float* __restrict__ out)
{
    int w = (blockIdx.x * blockDim.x + threadIdx.x) >> 6;
    int lane = threadIdx.x & 63;
    if (w >= N_NODES) return;
    float d2v = d2[w];
    float aev = ae2[0];
    int c = lane < C2 ? lane : 0;
    int jb = rowptr[w], je = rowptr[w + 1];
    float den = 0.f, acc = 0.f;
    for (int base = jb; base < je; base += 64) {
        int idx = base + lane;
        bool valid = idx < je;
        int2 ed = edges[valid ? idx : jb];
        float l = lrelu(s2[ed.x] + d2v + __int_as_float(ed.y) * aev);
        float p = valid ? __expf(l) : 0.f;
        int cnt = min(64, je - base);
        #pragma unroll 4
        for (int e = 0; e < cnt; ++e) {
            float pe = __shfl(p, e);
            int   se = __shfl(ed.x, e);
            den += pe;
            acc = fmaf(pe, bf2f(H2[(size_t)se * C1 + c]), acc);
        }
    }
    float o = acc / (den + 1e-16f);
    float v = lane < C2 ? o : -INFINITY;
    float m = v;
    #pragma unroll
    for (int off = 32; off; off >>= 1) m = fmaxf(m, __shfl_xor(m, off));
    float p = lane < C2 ? __expf(v - m) : 0.f;
    #pragma unroll
    for (int off = 32; off; off >>= 1) p += __shfl_xor(p, off);
    float ls = __logf(p);
    if (lane < C2) out[(size_t)w * C2 + lane] = v - m - ls;
}

extern "C" void kernel_launch(void* const* d_in, const int* in_sizes, int n_in,
                              void* d_out, int out_size, void* d_ws, size_t ws_size,
                              hipStream_t stream)
{
    const float* x   = (const float*)d_in[0];
    const int*   ei  = (const int*)  d_in[1];
    const float* ea  = (const float*)d_in[2];
    const float* W1  = (const float*)d_in[3];
    const float* as1 = (const float*)d_in[4];
    const float* ad1 = (const float*)d_in[5];
    const float* ae1 = (const float*)d_in[6];
    const float* W2  = (const float*)d_in[7];
    const float* as2 = (const float*)d_in[8];
    const float* ad2 = (const float*)d_in[9];
    const float* ae2 = (const float*)d_in[10];
    float* out = (float*)d_out;

    // workspace layout (4-byte units) — ~47 MB total
    float*    ws     = (float*)d_ws;
    ushort_t* H1     = (ushort_t*)ws;                 // 6.4M bf16 = 3.2M units
    ushort_t* H2     = (ushort_t*)(ws + 3200000);     // 6.4M bf16 (stride-64 padded)
    float*    s1     = ws + 6400000;                  // 800,000
    float*    d1     = ws + 7200000;                  // 800,000
    float*    s2     = ws + 8000000;                  // 100,000
    float*    d2     = ws + 8100000;                  // 100,000
    int*      deg    = (int*)(ws + 8200000);          // 100,000
    int*      rowptr = (int*)(ws + 8300000);          // 100,001
    int*      cur    = (int*)(ws + 8400008);          // 100,000
    int2*     edges  = (int2*)(ws + 8500008);         // 1.6M int2 = 3.2M units
    int*      bsum   = (int*)(ws + 11700008);         // 391
    int*      boff   = (int*)(ws + 11700400);         // 391

    hipMemsetAsync(deg, 0, 100000 * 4, stream);
    hipMemsetAsync(cur, 0, 100000 * 4, stream);

    k_gemm1     <<<N_NODES / 4, 256, 0, stream>>>(x, W1, as1, ad1, H1, s1, d1);
    k_count     <<<(N_EDGES + 255) / 256, 256, 0, stream>>>(ei, deg);
    k_red       <<<N_SBLK, SCAN_B, 0, stream>>>(deg, bsum);
    k_scan_small<<<1, 512, 0, stream>>>(bsum, boff, rowptr);
    k_apply     <<<N_SBLK, SCAN_B, 0, stream>>>(deg, boff, rowptr);
    k_fill      <<<(N_EDGES + 255) / 256, 256, 0, stream>>>(ei, ea, rowptr, cur, edges);
    k_node1     <<<(N_NODES + 3) / 4, 256, 0, stream>>>(rowptr, edges, s1, d1, ae1,
                                                        H1, W2, as2, ad2, H2, s2, d2);
    k_node2     <<<(N_NODES + 3) / 4, 256, 0, stream>>>(rowptr, edges, s2, d2, ae2,
                                                        H2, out);
}